// Round 1
// baseline (303.744 us; speedup 1.0000x reference)
//
#include <hip/hip_runtime.h>

typedef __attribute__((ext_vector_type(8))) short s8v;       // 8 x bf16 bits
typedef __attribute__((ext_vector_type(4))) float f32x4;
typedef __attribute__((ext_vector_type(4))) unsigned short u16x4;

#define SEQ 4096
#define DM  768
#define NH  12
#define HD  64

__device__ __forceinline__ unsigned short f2bf(float f) {
  union { float f; unsigned int u; } v; v.f = f;
  unsigned int r = v.u + 0x7fffu + ((v.u >> 16) & 1u);
  return (unsigned short)(r >> 16);
}

__device__ __forceinline__ void gload16(const void* g, void* l) {
  __builtin_amdgcn_global_load_lds((const __attribute__((address_space(1))) void*)g,
                                   (__attribute__((address_space(3))) void*)l, 16, 0, 0);
}

// ---------------- elementwise cast fp32 -> bf16 ----------------
__global__ __launch_bounds__(256) void k_cast(const float* __restrict__ in,
                                              unsigned short* __restrict__ out) {
  int i = (blockIdx.x * 256 + threadIdx.x) * 4;
  float4 v = *reinterpret_cast<const float4*>(in + i);
  u16x4 o;
  o.x = f2bf(v.x); o.y = f2bf(v.y); o.z = f2bf(v.z); o.w = f2bf(v.w);
  *reinterpret_cast<u16x4*>(out + i) = o;
}

// ---------------- transpose + cast: in [K][N] f32 -> out [N][K] bf16 ----------------
__global__ __launch_bounds__(256) void k_transpose_cast(const float* __restrict__ in,
                                                        unsigned short* __restrict__ out,
                                                        int K, int N) {
  __shared__ float tile[32][33];
  int k0 = blockIdx.x * 32, n0 = blockIdx.y * 32;
  int tr = threadIdx.x >> 5, tc = threadIdx.x & 31;
#pragma unroll
  for (int i = 0; i < 4; i++)
    tile[i * 8 + tr][tc] = in[(k0 + i * 8 + tr) * N + n0 + tc];
  __syncthreads();
#pragma unroll
  for (int i = 0; i < 4; i++)
    out[(n0 + i * 8 + tr) * K + k0 + tc] = f2bf(tile[tc][i * 8 + tr]);
}

// ---------------- 128x128 bf16 MFMA GEMM, A[M][768] @ BT[N][768]^T ----------------
// MODE 0: QKV epilogue -> Oq/Ok row-major bf16, Ov transposed per head-dim column
// MODE 1: fp32 output + bias -> Of
template<int MODE>
__global__ __launch_bounds__(256) void k_gemm(
    const unsigned short* __restrict__ A, const unsigned short* __restrict__ BT,
    const float* __restrict__ bias,
    unsigned short* __restrict__ Oq, unsigned short* __restrict__ Ok,
    unsigned short* __restrict__ Ov, float* __restrict__ Of) {
  __shared__ unsigned short As[128 * 32];
  __shared__ unsigned short Bs[128 * 32];
  const int tid = threadIdx.x;
  const int lane = tid & 63;
  const int w = tid >> 6;
  const int wm = w >> 1, wn = w & 1;
  const int l15 = lane & 15, l4 = lane >> 4;
  const int m0 = blockIdx.x * 128, n0 = blockIdx.y * 128;

  f32x4 acc[4][4] = {};

  // staging descriptors: slot t stores global k-chunk kc = (t&3) ^ ((row>>1)&3)
  int srow[2], skc[2];
#pragma unroll
  for (int j = 0; j < 2; j++) {
    int slot = j * 256 + tid;
    srow[j] = slot >> 2;
    skc[j] = (slot & 3) ^ ((srow[j] >> 1) & 3);
  }
  const int ldsb0 = (tid & ~63) * 16;          // wave-uniform byte base, call 0
  const int ldsb1 = (256 + (tid & ~63)) * 16;  // call 1

  for (int k0 = 0; k0 < DM; k0 += 32) {
    gload16(A + (m0 + srow[0]) * DM + k0 + skc[0] * 8, (char*)As + ldsb0);
    gload16(A + (m0 + srow[1]) * DM + k0 + skc[1] * 8, (char*)As + ldsb1);
    gload16(BT + (n0 + srow[0]) * DM + k0 + skc[0] * 8, (char*)Bs + ldsb0);
    gload16(BT + (n0 + srow[1]) * DM + k0 + skc[1] * 8, (char*)Bs + ldsb1);
    __syncthreads();
    s8v af[4], bfr[4];
#pragma unroll
    for (int i = 0; i < 4; i++) {
      int ra = wm * 64 + i * 16 + l15;
      int ca = (l4 ^ ((ra >> 1) & 3)) * 8;
      af[i] = *reinterpret_cast<const s8v*>(&As[ra * 32 + ca]);
      int rb = wn * 64 + i * 16 + l15;
      int cb = (l4 ^ ((rb >> 1) & 3)) * 8;
      bfr[i] = *reinterpret_cast<const s8v*>(&Bs[rb * 32 + cb]);
    }
#pragma unroll
    for (int mi = 0; mi < 4; mi++)
#pragma unroll
      for (int nj = 0; nj < 4; nj++)
        acc[mi][nj] = __builtin_amdgcn_mfma_f32_16x16x32_bf16(af[mi], bfr[nj], acc[mi][nj], 0, 0, 0);
    __syncthreads();
  }

#pragma unroll
  for (int nj = 0; nj < 4; nj++) {
    const int col = n0 + wn * 64 + nj * 16 + l15;
    const float bv = bias[col];
#pragma unroll
    for (int mi = 0; mi < 4; mi++) {
      const int rowb = m0 + wm * 64 + mi * 16 + l4 * 4;
      if (MODE == 0) {
        if (col < 768) {
#pragma unroll
          for (int r = 0; r < 4; r++)
            Oq[(rowb + r) * DM + col] = f2bf(acc[mi][nj][r] + bv);
        } else if (col < 1536) {
#pragma unroll
          for (int r = 0; r < 4; r++)
            Ok[(rowb + r) * DM + (col - 768)] = f2bf(acc[mi][nj][r] + bv);
        } else {
          u16x4 pk;
#pragma unroll
          for (int r = 0; r < 4; r++)
            pk[r] = f2bf(acc[mi][nj][r] + bv);
          *reinterpret_cast<u16x4*>(&Ov[(col - 1536) * SEQ + rowb]) = pk;
        }
      } else {
#pragma unroll
        for (int r = 0; r < 4; r++)
          Of[(rowb + r) * DM + col] = acc[mi][nj][r] + bv;
      }
    }
  }
}

// ---------------- causal flash attention ----------------
// 4 waves/block, 16 q-rows per wave, 64 keys per iteration.
// Qb/Kb: [S][768] bf16 (head h at cols h*64..); Vt: [h*64+d][S] bf16.
__global__ __launch_bounds__(256) void k_attn(
    const unsigned short* __restrict__ Qb, const unsigned short* __restrict__ Kb,
    const unsigned short* __restrict__ Vt, unsigned short* __restrict__ Aout) {
  __shared__ unsigned char Pl[4][2048];  // per-wave P buffer (16 rows x 64 keys bf16, XOR-swizzled)
  const int tid = threadIdx.x;
  const int lane = tid & 63;
  const int w = tid >> 6;
  const int l15 = lane & 15, l4 = lane >> 4;
  const int bid = blockIdx.x;
  const int h = bid % NH;
  const int qt = 63 - (bid / NH);   // heavy q-tiles dispatch first
  const int q0 = qt * 64 + w * 16;

  s8v aq[2];
#pragma unroll
  for (int kc = 0; kc < 2; kc++)
    aq[kc] = *reinterpret_cast<const s8v*>(&Qb[(q0 + l15) * DM + h * HD + kc * 32 + l4 * 8]);

  f32x4 O[4] = {};
  float mrow[4] = {-1e30f, -1e30f, -1e30f, -1e30f};
  float lrow[4] = {0.f, 0.f, 0.f, 0.f};

  const int ntiles = (q0 + 15) / 64 + 1;
  for (int t = 0; t < ntiles; t++) {
    const int kb = t * 64;
    float p[4][4];  // [c2][r]
#pragma unroll
    for (int c2 = 0; c2 < 4; c2++) {
      f32x4 z = {};
#pragma unroll
      for (int kc = 0; kc < 2; kc++) {
        s8v bk = *reinterpret_cast<const s8v*>(
            &Kb[(kb + c2 * 16 + l15) * DM + h * HD + kc * 32 + l4 * 8]);
        z = __builtin_amdgcn_mfma_f32_16x16x32_bf16(aq[kc], bk, z, 0, 0, 0);
      }
      const int key = kb + c2 * 16 + l15;
#pragma unroll
      for (int r = 0; r < 4; r++) {
        float sv = z[r] * 0.125f;
        p[c2][r] = (key > q0 + l4 * 4 + r) ? -1e30f : sv;
      }
    }
    float alpha[4], rsum[4];
#pragma unroll
    for (int r = 0; r < 4; r++) {
      float tm = fmaxf(fmaxf(p[0][r], p[1][r]), fmaxf(p[2][r], p[3][r]));
#pragma unroll
      for (int off = 1; off < 16; off <<= 1)
        tm = fmaxf(tm, __shfl_xor(tm, off));
      float mn = fmaxf(mrow[r], tm);
      alpha[r] = __expf(mrow[r] - mn);
      mrow[r] = mn;
      float s = 0.f;
#pragma unroll
      for (int c2 = 0; c2 < 4; c2++) {
        float e = __expf(p[c2][r] - mn);
        p[c2][r] = e;
        s += e;
      }
      rsum[r] = s;
    }
#pragma unroll
    for (int r = 0; r < 4; r++) {
#pragma unroll
      for (int off = 1; off < 16; off <<= 1)
        rsum[r] += __shfl_xor(rsum[r], off);
      lrow[r] = lrow[r] * alpha[r] + rsum[r];
    }
#pragma unroll
    for (int dc = 0; dc < 4; dc++)
#pragma unroll
      for (int r = 0; r < 4; r++)
        O[dc][r] *= alpha[r];
    // P -> LDS (row m, byte-col bc; 16B-chunk XOR swizzle by row to kill bank conflicts)
#pragma unroll
    for (int c2 = 0; c2 < 4; c2++) {
#pragma unroll
      for (int r = 0; r < 4; r++) {
        int m = l4 * 4 + r;
        int bc = c2 * 32 + l15 * 2;
        int addr = m * 128 + (((bc >> 4) ^ (m & 7)) << 4) + (bc & 15);
        *reinterpret_cast<unsigned short*>(&Pl[w][addr]) = f2bf(p[c2][r]);
      }
    }
    __asm__ volatile("s_waitcnt lgkmcnt(0)" ::: "memory");
    s8v pa[2];
#pragma unroll
    for (int kc2 = 0; kc2 < 2; kc2++) {
      int chunk = kc2 * 4 + l4;
      int addr = l15 * 128 + ((chunk ^ (l15 & 7)) << 4);
      pa[kc2] = *reinterpret_cast<const s8v*>(&Pl[w][addr]);
    }
#pragma unroll
    for (int dc = 0; dc < 4; dc++) {
#pragma unroll
      for (int kc2 = 0; kc2 < 2; kc2++) {
        s8v bv = *reinterpret_cast<const s8v*>(
            &Vt[(h * HD + dc * 16 + l15) * SEQ + kb + kc2 * 32 + l4 * 8]);
        O[dc] = __builtin_amdgcn_mfma_f32_16x16x32_bf16(pa[kc2], bv, O[dc], 0, 0, 0);
      }
    }
  }
  float rinv[4];
#pragma unroll
  for (int r = 0; r < 4; r++) rinv[r] = 1.f / lrow[r];
#pragma unroll
  for (int dc = 0; dc < 4; dc++)
#pragma unroll
    for (int r = 0; r < 4; r++)
      Aout[(q0 + l4 * 4 + r) * DM + h * HD + dc * 16 + l15] = f2bf(O[dc][r] * rinv[r]);
}

extern "C" void kernel_launch(void* const* d_in, const int* in_sizes, int n_in,
                              void* d_out, int out_size, void* d_ws, size_t ws_size,
                              hipStream_t stream) {
  (void)in_sizes; (void)n_in; (void)out_size; (void)ws_size;
  const float* tokens = (const float*)d_in[0];
  // d_in[1] = attn_bias (causal tril) — causality is hardcoded in k_attn
  const float* wqkv  = (const float*)d_in[2];
  const float* bqkv  = (const float*)d_in[3];
  const float* wproj = (const float*)d_in[4];
  const float* bproj = (const float*)d_in[5];
  float* out = (float*)d_out;

  unsigned short* tok    = (unsigned short*)d_ws;       // [4096][768]
  unsigned short* wqkvT  = tok + 4096 * 768;            // [2304][768]
  unsigned short* wprojT = wqkvT + 2304 * 768;          // [768][768]
  unsigned short* Qb     = wprojT + 768 * 768;          // [4096][768]
  unsigned short* Kb     = Qb + 4096 * 768;             // [4096][768]
  unsigned short* Vt     = Kb + 4096 * 768;             // [768][4096]
  unsigned short* attn   = Vt + 768 * 4096;             // [4096][768]

  k_cast<<<3072, 256, 0, stream>>>(tokens, tok);
  k_transpose_cast<<<dim3(24, 72), 256, 0, stream>>>(wqkv, wqkvT, 768, 2304);
  k_transpose_cast<<<dim3(24, 24), 256, 0, stream>>>(wproj, wprojT, 768, 768);
  k_gemm<0><<<dim3(32, 18), 256, 0, stream>>>(tok, wqkvT, bqkv, Qb, Kb, Vt, nullptr);
  k_attn<<<768, 256, 0, stream>>>(Qb, Kb, Vt, attn);
  k_gemm<1><<<dim3(32, 6), 256, 0, stream>>>(attn, wprojT, bproj, nullptr, nullptr, nullptr, out);
}

// Round 2
// 236.841 us; speedup vs baseline: 1.2825x; 1.2825x over previous
//
#include <hip/hip_runtime.h>

typedef __attribute__((ext_vector_type(8))) short s8v;       // 8 x bf16 bits
typedef __attribute__((ext_vector_type(4))) float f32x4;
typedef __attribute__((ext_vector_type(4))) unsigned short u16x4;

#define SEQ 4096
#define DM  768
#define NH  12
#define HD  64

__device__ __forceinline__ unsigned short f2bf(float f) {
  union { float f; unsigned int u; } v; v.f = f;
  unsigned int r = v.u + 0x7fffu + ((v.u >> 16) & 1u);
  return (unsigned short)(r >> 16);
}

__device__ __forceinline__ void gload16(const void* g, void* l) {
  __builtin_amdgcn_global_load_lds((const __attribute__((address_space(1))) void*)g,
                                   (__attribute__((address_space(3))) void*)l, 16, 0, 0);
}

// ---------------- elementwise cast fp32 -> bf16 ----------------
__global__ __launch_bounds__(256) void k_cast(const float* __restrict__ in,
                                              unsigned short* __restrict__ out) {
  int i = (blockIdx.x * 256 + threadIdx.x) * 4;
  float4 v = *reinterpret_cast<const float4*>(in + i);
  u16x4 o;
  o.x = f2bf(v.x); o.y = f2bf(v.y); o.z = f2bf(v.z); o.w = f2bf(v.w);
  *reinterpret_cast<u16x4*>(out + i) = o;
}

// ---------------- transpose + cast: in [K][N] f32 -> out [N][K] bf16 ----------------
__global__ __launch_bounds__(256) void k_transpose_cast(const float* __restrict__ in,
                                                        unsigned short* __restrict__ out,
                                                        int K, int N) {
  __shared__ float tile[32][33];
  int k0 = blockIdx.x * 32, n0 = blockIdx.y * 32;
  int tr = threadIdx.x >> 5, tc = threadIdx.x & 31;
#pragma unroll
  for (int i = 0; i < 4; i++)
    tile[i * 8 + tr][tc] = in[(k0 + i * 8 + tr) * N + n0 + tc];
  __syncthreads();
#pragma unroll
  for (int i = 0; i < 4; i++)
    out[(n0 + i * 8 + tr) * K + k0 + tc] = f2bf(tile[tc][i * 8 + tr]);
}

// ---------------- 128x128 bf16 MFMA GEMM, A[M][768] @ BT[N][768]^T ----------------
template<int MODE>
__global__ __launch_bounds__(256) void k_gemm(
    const unsigned short* __restrict__ A, const unsigned short* __restrict__ BT,
    const float* __restrict__ bias,
    unsigned short* __restrict__ Oq, unsigned short* __restrict__ Ok,
    unsigned short* __restrict__ Ov, float* __restrict__ Of) {
  __shared__ unsigned short As[128 * 32];
  __shared__ unsigned short Bs[128 * 32];
  const int tid = threadIdx.x;
  const int lane = tid & 63;
  const int w = tid >> 6;
  const int wm = w >> 1, wn = w & 1;
  const int l15 = lane & 15, l4 = lane >> 4;
  const int m0 = blockIdx.x * 128, n0 = blockIdx.y * 128;

  f32x4 acc[4][4] = {};

  int srow[2], skc[2];
#pragma unroll
  for (int j = 0; j < 2; j++) {
    int slot = j * 256 + tid;
    srow[j] = slot >> 2;
    skc[j] = (slot & 3) ^ ((srow[j] >> 1) & 3);
  }
  const int ldsb0 = (tid & ~63) * 16;
  const int ldsb1 = (256 + (tid & ~63)) * 16;

  for (int k0 = 0; k0 < DM; k0 += 32) {
    gload16(A + (m0 + srow[0]) * DM + k0 + skc[0] * 8, (char*)As + ldsb0);
    gload16(A + (m0 + srow[1]) * DM + k0 + skc[1] * 8, (char*)As + ldsb1);
    gload16(BT + (n0 + srow[0]) * DM + k0 + skc[0] * 8, (char*)Bs + ldsb0);
    gload16(BT + (n0 + srow[1]) * DM + k0 + skc[1] * 8, (char*)Bs + ldsb1);
    __syncthreads();
    s8v af[4], bfr[4];
#pragma unroll
    for (int i = 0; i < 4; i++) {
      int ra = wm * 64 + i * 16 + l15;
      int ca = (l4 ^ ((ra >> 1) & 3)) * 8;
      af[i] = *reinterpret_cast<const s8v*>(&As[ra * 32 + ca]);
      int rb = wn * 64 + i * 16 + l15;
      int cb = (l4 ^ ((rb >> 1) & 3)) * 8;
      bfr[i] = *reinterpret_cast<const s8v*>(&Bs[rb * 32 + cb]);
    }
#pragma unroll
    for (int mi = 0; mi < 4; mi++)
#pragma unroll
      for (int nj = 0; nj < 4; nj++)
        acc[mi][nj] = __builtin_amdgcn_mfma_f32_16x16x32_bf16(af[mi], bfr[nj], acc[mi][nj], 0, 0, 0);
    __syncthreads();
  }

#pragma unroll
  for (int nj = 0; nj < 4; nj++) {
    const int col = n0 + wn * 64 + nj * 16 + l15;
    const float bv = bias[col];
#pragma unroll
    for (int mi = 0; mi < 4; mi++) {
      const int rowb = m0 + wm * 64 + mi * 16 + l4 * 4;
      if (MODE == 0) {
        if (col < 768) {
#pragma unroll
          for (int r = 0; r < 4; r++)
            Oq[(rowb + r) * DM + col] = f2bf(acc[mi][nj][r] + bv);
        } else if (col < 1536) {
#pragma unroll
          for (int r = 0; r < 4; r++)
            Ok[(rowb + r) * DM + (col - 768)] = f2bf(acc[mi][nj][r] + bv);
        } else {
          u16x4 pk;
#pragma unroll
          for (int r = 0; r < 4; r++)
            pk[r] = f2bf(acc[mi][nj][r] + bv);
          *reinterpret_cast<u16x4*>(&Ov[(col - 1536) * SEQ + rowb]) = pk;
        }
      } else {
#pragma unroll
        for (int r = 0; r < 4; r++)
          Of[(rowb + r) * DM + col] = acc[mi][nj][r] + bv;
      }
    }
  }
}

// ---------------- causal flash attention, 4-way key-split ----------------
// Block: 16 q-rows of one head. 4 waves each take key-tiles t = w, w+4, ...
// with private online-softmax state (log2 domain); merged via LDS at the end.
// Qb/Kb: [S][768] bf16 (head h at cols h*64..); Vt: [h*64+d][S] bf16.
__global__ __launch_bounds__(256) void k_attn(
    const unsigned short* __restrict__ Qb, const unsigned short* __restrict__ Kb,
    const unsigned short* __restrict__ Vt, unsigned short* __restrict__ Aout) {
  __shared__ unsigned char Pl[4][2048];  // per-wave P buffer (16x64 bf16, XOR-swizzled)
  __shared__ float Os[4][16][68];        // per-wave O partials (+pad for banks)
  __shared__ float Ml[4][2][16];         // per-wave m (log2) and l per q-row
  const int tid = threadIdx.x;
  const int lane = tid & 63;
  const int w = tid >> 6;
  const int l15 = lane & 15, l4 = lane >> 4;
  const int bid = blockIdx.x;
  const int h = bid % NH;
  const int qt = 255 - (bid / NH);      // heavy q-tiles dispatch first
  const int q0 = qt * 16;
  const int ntiles = (q0 + 15) / 64 + 1;
  const float SCL = 0.125f * 1.44269504f;  // (1/sqrt(hd)) * log2(e)

  s8v aq[2];
#pragma unroll
  for (int kc = 0; kc < 2; kc++)
    aq[kc] = *reinterpret_cast<const s8v*>(&Qb[(q0 + l15) * DM + h * HD + kc * 32 + l4 * 8]);

  f32x4 O[4] = {};
  float mrow[4] = {-1e30f, -1e30f, -1e30f, -1e30f};
  float lrow[4] = {0.f, 0.f, 0.f, 0.f};

  for (int t = w; t < ntiles; t += 4) {
    const int kb = t * 64;
    float p[4][4];  // [c2][r], log2 domain
#pragma unroll
    for (int c2 = 0; c2 < 4; c2++) {
      f32x4 z = {};
#pragma unroll
      for (int kc = 0; kc < 2; kc++) {
        s8v bk = *reinterpret_cast<const s8v*>(
            &Kb[(kb + c2 * 16 + l15) * DM + h * HD + kc * 32 + l4 * 8]);
        z = __builtin_amdgcn_mfma_f32_16x16x32_bf16(aq[kc], bk, z, 0, 0, 0);
      }
      const int key = kb + c2 * 16 + l15;
#pragma unroll
      for (int r = 0; r < 4; r++)
        p[c2][r] = (key > q0 + l4 * 4 + r) ? -1e30f : z[r] * SCL;
    }
    // prefetch V for this tile (latency hides under softmax)
    s8v vv[4][2];
#pragma unroll
    for (int dc = 0; dc < 4; dc++)
#pragma unroll
      for (int kc2 = 0; kc2 < 2; kc2++)
        vv[dc][kc2] = *reinterpret_cast<const s8v*>(
            &Vt[(h * HD + dc * 16 + l15) * SEQ + kb + kc2 * 32 + l4 * 8]);
    // online softmax (log2 domain), per-row reduce across 16 lanes
    float alpha[4], rsum[4];
#pragma unroll
    for (int r = 0; r < 4; r++) {
      float tm = fmaxf(fmaxf(p[0][r], p[1][r]), fmaxf(p[2][r], p[3][r]));
#pragma unroll
      for (int off = 1; off < 16; off <<= 1)
        tm = fmaxf(tm, __shfl_xor(tm, off));
      float mn = fmaxf(mrow[r], tm);
      alpha[r] = exp2f(mrow[r] - mn);
      mrow[r] = mn;
      float s = 0.f;
#pragma unroll
      for (int c2 = 0; c2 < 4; c2++) {
        float e = exp2f(p[c2][r] - mn);
        p[c2][r] = e;
        s += e;
      }
      rsum[r] = s;
    }
#pragma unroll
    for (int r = 0; r < 4; r++) {
#pragma unroll
      for (int off = 1; off < 16; off <<= 1)
        rsum[r] += __shfl_xor(rsum[r], off);
      lrow[r] = lrow[r] * alpha[r] + rsum[r];
    }
#pragma unroll
    for (int dc = 0; dc < 4; dc++)
#pragma unroll
      for (int r = 0; r < 4; r++)
        O[dc][r] *= alpha[r];
    // P -> LDS (16B-chunk XOR swizzle by row)
#pragma unroll
    for (int c2 = 0; c2 < 4; c2++) {
#pragma unroll
      for (int r = 0; r < 4; r++) {
        int m = l4 * 4 + r;
        int bc = c2 * 32 + l15 * 2;
        int addr = m * 128 + (((bc >> 4) ^ (m & 7)) << 4) + (bc & 15);
        *reinterpret_cast<unsigned short*>(&Pl[w][addr]) = f2bf(p[c2][r]);
      }
    }
    __asm__ volatile("s_waitcnt lgkmcnt(0)" ::: "memory");
    s8v pa[2];
#pragma unroll
    for (int kc2 = 0; kc2 < 2; kc2++) {
      int chunk = kc2 * 4 + l4;
      int addr = l15 * 128 + ((chunk ^ (l15 & 7)) << 4);
      pa[kc2] = *reinterpret_cast<const s8v*>(&Pl[w][addr]);
    }
#pragma unroll
    for (int dc = 0; dc < 4; dc++)
#pragma unroll
      for (int kc2 = 0; kc2 < 2; kc2++)
        O[dc] = __builtin_amdgcn_mfma_f32_16x16x32_bf16(pa[kc2], vv[dc][kc2], O[dc], 0, 0, 0);
  }

  // ---- publish per-wave state ----
#pragma unroll
  for (int dc = 0; dc < 4; dc++)
#pragma unroll
    for (int r = 0; r < 4; r++)
      Os[w][l4 * 4 + r][dc * 16 + l15] = O[dc][r];
  if (l15 == 0) {
#pragma unroll
    for (int r = 0; r < 4; r++) {
      Ml[w][0][l4 * 4 + r] = mrow[r];
      Ml[w][1][l4 * 4 + r] = lrow[r];
    }
  }
  __syncthreads();

  // ---- merge 4 partials; wave w writes output cols [w*16, w*16+16) ----
#pragma unroll
  for (int r = 0; r < 4; r++) {
    const int row = l4 * 4 + r;
    float m0 = Ml[0][0][row], m1 = Ml[1][0][row], m2 = Ml[2][0][row], m3 = Ml[3][0][row];
    float ms = fmaxf(fmaxf(m0, m1), fmaxf(m2, m3));
    float s0 = exp2f(m0 - ms), s1 = exp2f(m1 - ms), s2 = exp2f(m2 - ms), s3 = exp2f(m3 - ms);
    float lsum = s0 * Ml[0][1][row] + s1 * Ml[1][1][row] + s2 * Ml[2][1][row] + s3 * Ml[3][1][row];
    float acc = s0 * Os[0][row][w * 16 + l15] + s1 * Os[1][row][w * 16 + l15] +
                s2 * Os[2][row][w * 16 + l15] + s3 * Os[3][row][w * 16 + l15];
    Aout[(q0 + row) * DM + h * HD + w * 16 + l15] = f2bf(acc / lsum);
  }
}

extern "C" void kernel_launch(void* const* d_in, const int* in_sizes, int n_in,
                              void* d_out, int out_size, void* d_ws, size_t ws_size,
                              hipStream_t stream) {
  (void)in_sizes; (void)n_in; (void)out_size; (void)ws_size;
  const float* tokens = (const float*)d_in[0];
  const float* wqkv  = (const float*)d_in[2];
  const float* bqkv  = (const float*)d_in[3];
  const float* wproj = (const float*)d_in[4];
  const float* bproj = (const float*)d_in[5];
  float* out = (float*)d_out;

  unsigned short* tok    = (unsigned short*)d_ws;       // [4096][768]
  unsigned short* wqkvT  = tok + 4096 * 768;            // [2304][768]
  unsigned short* wprojT = wqkvT + 2304 * 768;          // [768][768]
  unsigned short* Qb     = wprojT + 768 * 768;          // [4096][768]
  unsigned short* Kb     = Qb + 4096 * 768;             // [4096][768]
  unsigned short* Vt     = Kb + 4096 * 768;             // [768][4096]
  unsigned short* attn   = Vt + 768 * 4096;             // [4096][768]

  k_cast<<<3072, 256, 0, stream>>>(tokens, tok);
  k_transpose_cast<<<dim3(24, 72), 256, 0, stream>>>(wqkv, wqkvT, 768, 2304);
  k_transpose_cast<<<dim3(24, 24), 256, 0, stream>>>(wproj, wprojT, 768, 768);
  k_gemm<0><<<dim3(32, 18), 256, 0, stream>>>(tok, wqkvT, bqkv, Qb, Kb, Vt, nullptr);
  k_attn<<<3072, 256, 0, stream>>>(Qb, Kb, Vt, attn);
  k_gemm<1><<<dim3(32, 6), 256, 0, stream>>>(attn, wprojT, bproj, nullptr, nullptr, nullptr, out);
}

// Round 3
// 235.143 us; speedup vs baseline: 1.2917x; 1.0072x over previous
//
#include <hip/hip_runtime.h>

typedef __attribute__((ext_vector_type(8))) short s8v;       // 8 x bf16 bits
typedef __attribute__((ext_vector_type(4))) float f32x4;
typedef __attribute__((ext_vector_type(4))) unsigned short u16x4;
typedef __attribute__((ext_vector_type(2))) unsigned int u32x2;

#define SEQ 4096
#define DM  768
#define NH  12
#define HD  64

__device__ __forceinline__ unsigned short f2bf(float f) {
  union { float f; unsigned int u; } v; v.f = f;
  unsigned int r = v.u + 0x7fffu + ((v.u >> 16) & 1u);
  return (unsigned short)(r >> 16);
}

__device__ __forceinline__ unsigned int cvtpk(float lo, float hi) {
  unsigned int r;
  asm("v_cvt_pk_bf16_f32 %0, %1, %2" : "=v"(r) : "v"(lo), "v"(hi));
  return r;
}

__device__ __forceinline__ void gload16(const void* g, void* l) {
  __builtin_amdgcn_global_load_lds((const __attribute__((address_space(1))) void*)g,
                                   (__attribute__((address_space(3))) void*)l, 16, 0, 0);
}

// ---------------- elementwise cast fp32 -> bf16 ----------------
__global__ __launch_bounds__(256) void k_cast(const float* __restrict__ in,
                                              unsigned short* __restrict__ out) {
  int i = (blockIdx.x * 256 + threadIdx.x) * 4;
  float4 v = *reinterpret_cast<const float4*>(in + i);
  u16x4 o;
  o.x = f2bf(v.x); o.y = f2bf(v.y); o.z = f2bf(v.z); o.w = f2bf(v.w);
  *reinterpret_cast<u16x4*>(out + i) = o;
}

// ---------------- transpose + cast: in [K][N] f32 -> out [N][K] bf16 ----------------
__global__ __launch_bounds__(256) void k_transpose_cast(const float* __restrict__ in,
                                                        unsigned short* __restrict__ out,
                                                        int K, int N) {
  __shared__ float tile[32][33];
  int k0 = blockIdx.x * 32, n0 = blockIdx.y * 32;
  int tr = threadIdx.x >> 5, tc = threadIdx.x & 31;
#pragma unroll
  for (int i = 0; i < 4; i++)
    tile[i * 8 + tr][tc] = in[(k0 + i * 8 + tr) * N + n0 + tc];
  __syncthreads();
#pragma unroll
  for (int i = 0; i < 4; i++)
    out[(n0 + i * 8 + tr) * K + k0 + tc] = f2bf(tile[tc][i * 8 + tr]);
}

// ---------------- 128x128 bf16 MFMA GEMM, A[M][768] @ BT[N][768]^T ----------------
template<int MODE>
__global__ __launch_bounds__(256) void k_gemm(
    const unsigned short* __restrict__ A, const unsigned short* __restrict__ BT,
    const float* __restrict__ bias,
    unsigned short* __restrict__ Oq, unsigned short* __restrict__ Ok,
    unsigned short* __restrict__ Ov, float* __restrict__ Of) {
  __shared__ unsigned short As[128 * 32];
  __shared__ unsigned short Bs[128 * 32];
  const int tid = threadIdx.x;
  const int lane = tid & 63;
  const int w = tid >> 6;
  const int wm = w >> 1, wn = w & 1;
  const int l15 = lane & 15, l4 = lane >> 4;
  const int m0 = blockIdx.x * 128, n0 = blockIdx.y * 128;

  f32x4 acc[4][4] = {};

  int srow[2], skc[2];
#pragma unroll
  for (int j = 0; j < 2; j++) {
    int slot = j * 256 + tid;
    srow[j] = slot >> 2;
    skc[j] = (slot & 3) ^ ((srow[j] >> 1) & 3);
  }
  const int ldsb0 = (tid & ~63) * 16;
  const int ldsb1 = (256 + (tid & ~63)) * 16;

  for (int k0 = 0; k0 < DM; k0 += 32) {
    gload16(A + (m0 + srow[0]) * DM + k0 + skc[0] * 8, (char*)As + ldsb0);
    gload16(A + (m0 + srow[1]) * DM + k0 + skc[1] * 8, (char*)As + ldsb1);
    gload16(BT + (n0 + srow[0]) * DM + k0 + skc[0] * 8, (char*)Bs + ldsb0);
    gload16(BT + (n0 + srow[1]) * DM + k0 + skc[1] * 8, (char*)Bs + ldsb1);
    __syncthreads();
    s8v af[4], bfr[4];
#pragma unroll
    for (int i = 0; i < 4; i++) {
      int ra = wm * 64 + i * 16 + l15;
      int ca = (l4 ^ ((ra >> 1) & 3)) * 8;
      af[i] = *reinterpret_cast<const s8v*>(&As[ra * 32 + ca]);
      int rb = wn * 64 + i * 16 + l15;
      int cb = (l4 ^ ((rb >> 1) & 3)) * 8;
      bfr[i] = *reinterpret_cast<const s8v*>(&Bs[rb * 32 + cb]);
    }
#pragma unroll
    for (int mi = 0; mi < 4; mi++)
#pragma unroll
      for (int nj = 0; nj < 4; nj++)
        acc[mi][nj] = __builtin_amdgcn_mfma_f32_16x16x32_bf16(af[mi], bfr[nj], acc[mi][nj], 0, 0, 0);
    __syncthreads();
  }

#pragma unroll
  for (int nj = 0; nj < 4; nj++) {
    const int col = n0 + wn * 64 + nj * 16 + l15;
    const float bv = bias[col];
#pragma unroll
    for (int mi = 0; mi < 4; mi++) {
      const int rowb = m0 + wm * 64 + mi * 16 + l4 * 4;
      if (MODE == 0) {
        if (col < 768) {
#pragma unroll
          for (int r = 0; r < 4; r++)
            Oq[(rowb + r) * DM + col] = f2bf(acc[mi][nj][r] + bv);
        } else if (col < 1536) {
#pragma unroll
          for (int r = 0; r < 4; r++)
            Ok[(rowb + r) * DM + (col - 768)] = f2bf(acc[mi][nj][r] + bv);
        } else {
          u16x4 pk;
#pragma unroll
          for (int r = 0; r < 4; r++)
            pk[r] = f2bf(acc[mi][nj][r] + bv);
          *reinterpret_cast<u16x4*>(&Ov[(col - 1536) * SEQ + rowb]) = pk;
        }
      } else {
#pragma unroll
        for (int r = 0; r < 4; r++)
          Of[(rowb + r) * DM + col] = acc[mi][nj][r] + bv;
      }
    }
  }
}

// ---------------- causal flash attention, swapped-operand softmax ----------------
// Block: 16 q-rows of one head; 4 waves key-split (t = w, w+4, ...).
// Swapped QK^T: S^T[key][q], q = lane&15 lane-local -> in-lane softmax.
// Swapped PV: O^T[d][q] accumulator. Merge partials via LDS at the end.
__global__ __launch_bounds__(256) void k_attn(
    const unsigned short* __restrict__ Qb, const unsigned short* __restrict__ Kb,
    const unsigned short* __restrict__ Vt, unsigned short* __restrict__ Aout) {
  __shared__ unsigned char Pl[4][2048];  // per-wave P^T buffer (16 q-rows x 64 keys bf16, swizzled)
  __shared__ float Os[4][16][68];        // per-wave O partials [q][d] (+pad)
  __shared__ float Ml[4][2][16];         // per-wave m,l per q-row
  const int tid = threadIdx.x;
  const int lane = tid & 63;
  const int w = tid >> 6;
  const int l15 = lane & 15, l4 = lane >> 4;
  const int bid = blockIdx.x;
  const int h = bid % NH;
  const int qt = 255 - (bid / NH);      // heavy q-tiles dispatch first
  const int q0 = qt * 16;
  const int ntiles = q0 / 64 + 1;
  const float SCL = 0.125f * 1.44269504f;  // (1/sqrt(hd)) * log2(e)

  // Q fragment (B-operand of swapped QK): lane holds Q[q0+l15][kc*32 + l4*8 ..+7]
  s8v aq[2];
#pragma unroll
  for (int kc = 0; kc < 2; kc++)
    aq[kc] = *reinterpret_cast<const s8v*>(&Qb[(q0 + l15) * DM + h * HD + kc * 32 + l4 * 8]);

  // loop-invariant per-lane LDS byte offsets (XOR swizzle by q-row)
  unsigned char* const pw = (unsigned char*)&Pl[w][0];
  const int swz = (l15 & 7) << 4;
  const int wr_base = l15 * 128 + l4 * 8;    // + c2*32, ^ swz
  const int rd_base = l15 * 128 + l4 * 16;   // + kc2*64, ^ swz
  const int lanediff = l15 - l4 * 4;

  f32x4 Ot[4] = {};                          // Ot[dc][r] = O[q=l15][d = dc*16 + l4*4 + r]
  float m = -1e30f, lsum = 0.f;

  for (int t = w; t < ntiles; t += 4) {
    const int kb = t * 64;
    // V prefetch (A-operand of swapped PV): V^T[d=l15(+dc*16)][keys kc2*32+l4*8..]
    s8v av[4][2];
#pragma unroll
    for (int dc = 0; dc < 4; dc++)
#pragma unroll
      for (int kc2 = 0; kc2 < 2; kc2++)
        av[dc][kc2] = *reinterpret_cast<const s8v*>(
            &Vt[(h * HD + dc * 16 + l15) * SEQ + kb + kc2 * 32 + l4 * 8]);

    // swapped QK^T: raw scores, key = kb + c2*16 + l4*4 + r, q = q0 + l15
    float p[4][4];
#pragma unroll
    for (int c2 = 0; c2 < 4; c2++) {
      f32x4 z = {};
#pragma unroll
      for (int kc = 0; kc < 2; kc++) {
        s8v bk = *reinterpret_cast<const s8v*>(
            &Kb[(kb + c2 * 16 + l15) * DM + h * HD + kc * 32 + l4 * 8]);
        z = __builtin_amdgcn_mfma_f32_16x16x32_bf16(bk, aq[kc], z, 0, 0, 0);
      }
#pragma unroll
      for (int r = 0; r < 4; r++) p[c2][r] = z[r];
    }
    // causal mask: only the diagonal tile needs it (wave-uniform branch)
    if (kb + 63 > q0) {
      const int qml = q0 - kb + lanediff;   // mask if c2*16 + r > qml
#pragma unroll
      for (int c2 = 0; c2 < 4; c2++)
#pragma unroll
        for (int r = 0; r < 4; r++)
          p[c2][r] = (c2 * 16 + r > qml) ? -1e30f : p[c2][r];
    }
    // in-lane max tree (16 values) + cross-l4 reduce (2 shuffles)
    float t0 = fmaxf(fmaxf(p[0][0], p[0][1]), fmaxf(p[0][2], p[0][3]));
    float t1 = fmaxf(fmaxf(p[1][0], p[1][1]), fmaxf(p[1][2], p[1][3]));
    float t2 = fmaxf(fmaxf(p[2][0], p[2][1]), fmaxf(p[2][2], p[2][3]));
    float t3 = fmaxf(fmaxf(p[3][0], p[3][1]), fmaxf(p[3][2], p[3][3]));
    float tm = fmaxf(fmaxf(t0, t1), fmaxf(t2, t3));
    tm = fmaxf(tm, __shfl_xor(tm, 16));
    tm = fmaxf(tm, __shfl_xor(tm, 32));
    const float tsc = tm * SCL;
    // defer-max (T13): rescale only when tile max exceeds running max by >8 (log2)
    if (!__all(tsc <= m + 8.f)) {
      const float mn = fmaxf(m, tsc);
      const float al = exp2f(m - mn);
      m = mn;
      lsum *= al;
#pragma unroll
      for (int dc = 0; dc < 4; dc++)
#pragma unroll
        for (int r = 0; r < 4; r++) Ot[dc][r] *= al;
    }
    // exp (log2 domain), pack to bf16 pairs, write P^T row q=l15 to LDS
    float s = 0.f;
#pragma unroll
    for (int c2 = 0; c2 < 4; c2++) {
      float e0 = exp2f(fmaf(p[c2][0], SCL, -m));
      float e1 = exp2f(fmaf(p[c2][1], SCL, -m));
      float e2 = exp2f(fmaf(p[c2][2], SCL, -m));
      float e3 = exp2f(fmaf(p[c2][3], SCL, -m));
      s += (e0 + e1) + (e2 + e3);
      u32x2 pk;
      pk.x = cvtpk(e0, e1);
      pk.y = cvtpk(e2, e3);
      *reinterpret_cast<u32x2*>(pw + ((wr_base + c2 * 32) ^ swz)) = pk;
    }
    lsum += s;
    __asm__ volatile("s_waitcnt lgkmcnt(0)" ::: "memory");
    const s8v pb0 = *reinterpret_cast<const s8v*>(pw + ((rd_base) ^ swz));
    const s8v pb1 = *reinterpret_cast<const s8v*>(pw + ((rd_base + 64) ^ swz));
#pragma unroll
    for (int dc = 0; dc < 4; dc++) {
      Ot[dc] = __builtin_amdgcn_mfma_f32_16x16x32_bf16(av[dc][0], pb0, Ot[dc], 0, 0, 0);
      Ot[dc] = __builtin_amdgcn_mfma_f32_16x16x32_bf16(av[dc][1], pb1, Ot[dc], 0, 0, 0);
    }
  }

  // ---- publish per-wave state ----
  lsum += __shfl_xor(lsum, 16);
  lsum += __shfl_xor(lsum, 32);
#pragma unroll
  for (int dc = 0; dc < 4; dc++)
    *reinterpret_cast<f32x4*>(&Os[w][l15][dc * 16 + l4 * 4]) = Ot[dc];
  if (l4 == 0) {
    Ml[w][0][l15] = m;
    Ml[w][1][l15] = lsum;
  }
  __syncthreads();

  // ---- merge 4 partials; wave w writes output d-cols [w*16, w*16+16) ----
#pragma unroll
  for (int r = 0; r < 4; r++) {
    const int row = l4 * 4 + r;   // q-row
    float m0 = Ml[0][0][row], m1 = Ml[1][0][row], m2 = Ml[2][0][row], m3 = Ml[3][0][row];
    float ms = fmaxf(fmaxf(m0, m1), fmaxf(m2, m3));
    float s0 = exp2f(m0 - ms), s1 = exp2f(m1 - ms), s2 = exp2f(m2 - ms), s3 = exp2f(m3 - ms);
    float lsum4 = s0 * Ml[0][1][row] + s1 * Ml[1][1][row] + s2 * Ml[2][1][row] + s3 * Ml[3][1][row];
    float acc = s0 * Os[0][row][w * 16 + l15] + s1 * Os[1][row][w * 16 + l15] +
                s2 * Os[2][row][w * 16 + l15] + s3 * Os[3][row][w * 16 + l15];
    Aout[(q0 + row) * DM + h * HD + w * 16 + l15] = f2bf(acc / lsum4);
  }
}

extern "C" void kernel_launch(void* const* d_in, const int* in_sizes, int n_in,
                              void* d_out, int out_size, void* d_ws, size_t ws_size,
                              hipStream_t stream) {
  (void)in_sizes; (void)n_in; (void)out_size; (void)ws_size;
  const float* tokens = (const float*)d_in[0];
  const float* wqkv  = (const float*)d_in[2];
  const float* bqkv  = (const float*)d_in[3];
  const float* wproj = (const float*)d_in[4];
  const float* bproj = (const float*)d_in[5];
  float* out = (float*)d_out;

  unsigned short* tok    = (unsigned short*)d_ws;       // [4096][768]
  unsigned short* wqkvT  = tok + 4096 * 768;            // [2304][768]
  unsigned short* wprojT = wqkvT + 2304 * 768;          // [768][768]
  unsigned short* Qb     = wprojT + 768 * 768;          // [4096][768]
  unsigned short* Kb     = Qb + 4096 * 768;             // [4096][768]
  unsigned short* Vt     = Kb + 4096 * 768;             // [768][4096]
  unsigned short* attn   = Vt + 768 * 4096;             // [4096][768]

  k_cast<<<3072, 256, 0, stream>>>(tokens, tok);
  k_transpose_cast<<<dim3(24, 72), 256, 0, stream>>>(wqkv, wqkvT, 768, 2304);
  k_transpose_cast<<<dim3(24, 24), 256, 0, stream>>>(wproj, wprojT, 768, 768);
  k_gemm<0><<<dim3(32, 18), 256, 0, stream>>>(tok, wqkvT, bqkv, Qb, Kb, Vt, nullptr);
  k_attn<<<3072, 256, 0, stream>>>(Qb, Kb, Vt, attn);
  k_gemm<1><<<dim3(32, 6), 256, 0, stream>>>(attn, wprojT, bproj, nullptr, nullptr, nullptr, out);
}